// Round 1
// 575.794 us; speedup vs baseline: 1.5864x; 1.5864x over previous
//
#include <hip/hip_runtime.h>
#include <math.h>

// infoFSM mask-scorer MLP — Round 3: bf16x3 MFMA emulated-fp32 + exact-fix pass.
//
// Insight: the 55.9-GFLOP MLP only produces ONE BIT per row (prob*prev_m > 0.5).
// fp32 VALU roofline is 355us (no fp32 MFMA on CDNA4). Instead:
//   pass A: split weights into bf16 hi/lo (ws)                     (~3 us)
//   pass B: MLP via bf16x3 MFMA (a*b ~ ah*bh + ah*bl + al*bh),
//           logit error ~1e-5 << band. Decide + write out. Rows with
//           |v-0.5| < 1e-3 flagged to a list (atomic).             (~200 us)
//   pass C: flagged rows (~3%) recomputed in plain fp32, batched 8/block,
//           decisions overwritten (same numeric class as R2 kernel, absmax=0).
//
// Pass B per block: 32 rows. A-tile (hi/lo bf16, full K) staged ONCE into
// XOR-swizzled LDS -> only 5 barriers/block (R2 had 160). Weight frags are
// read per-lane straight from L2 (split weights = 1.7MB, L2-resident).
// GEMM1/2: v_mfma_f32_32x32x16_bf16 (acc 16 f32), GEMM3: 16x16x32 (8 n-tiles
// = 8 waves). Layer 4 (128->1) in fp32 VALU. Fragment layouts per verified
// m89/m101 mappings: A: [lane%W][8*(lane/W)+j], B: W[e=lane%W][k], D32:
// row=(r&3)+8*(r>>2)+4*(lane>>5), D16: row=(lane>>4)*4+r, col=lane&(W-1).

namespace {

constexpr int R_ROWS = 128 * 512;   // 65536
constexpr int D0 = 512, D1 = 512, D2 = 256, D3 = 128;
constexpr int TM = 32;              // rows per block (pass B)
constexpr int NT = 512;             // 8 waves

typedef __attribute__((ext_vector_type(8)))  short          vshort8;
typedef __attribute__((ext_vector_type(4)))  unsigned short vus4;
typedef __attribute__((ext_vector_type(16))) float          vf16;
typedef __attribute__((ext_vector_type(4)))  float          vf4;

// ---------------- helpers ----------------
__device__ __forceinline__ unsigned short f32_to_bf16(float x) {
    unsigned int b = __float_as_uint(x);
    b += 0x7FFFu + ((b >> 16) & 1u);          // RNE (inputs finite)
    return (unsigned short)(b >> 16);
}
__device__ __forceinline__ float bf16_to_f32(unsigned short h) {
    return __uint_as_float(((unsigned int)h) << 16);
}
__device__ __forceinline__ float gelu_exact(float x) {
    return 0.5f * x * (1.0f + erff(x * 0.70710678118654752440f));
}
__device__ __forceinline__ vf16 vzero16() {
    vf16 v;
    #pragma unroll
    for (int i = 0; i < 16; ++i) v[i] = 0.0f;
    return v;
}
__device__ __forceinline__ vf4 vzero4() {
    vf4 v;
    #pragma unroll
    for (int i = 0; i < 4; ++i) v[i] = 0.0f;
    return v;
}

// LDS activation tiles: [row][k] bf16, XOR-swizzle bits 4..6 (conflict-free
// frag reads: pitch multiple of 128B, rows 0..7 spread over 8 16B slots).
__device__ __forceinline__ int swz_off(int row, int colElem, int pitchB) {
    return (row * pitchB + colElem * 2) ^ ((row & 7) << 4);
}
__device__ __forceinline__ vshort8 ld_act32(const char* base, int lane, int pitchB, int k0) {
    const int row = lane & 31;
    const int k = k0 + ((lane >> 5) << 3);
    return *(const vshort8*)(base + swz_off(row, k, pitchB));
}
__device__ __forceinline__ vshort8 ld_act16(const char* base, int lane, int pitchB, int row0, int k0) {
    const int row = row0 + (lane & 15);
    const int k = k0 + ((lane >> 4) << 3);
    return *(const vshort8*)(base + swz_off(row, k, pitchB));
}
__device__ __forceinline__ vshort8 ld_w(const unsigned short* __restrict__ W, int K, int e, int k) {
    return *(const vshort8*)(W + e * K + k);
}
__device__ __forceinline__ void st_act(char* hi, char* lo, int row, int col, int pitchB, float x) {
    const unsigned short h = f32_to_bf16(x);
    const unsigned short l = f32_to_bf16(x - bf16_to_f32(h));
    const int off = swz_off(row, col, pitchB);
    *(unsigned short*)(hi + off) = h;
    *(unsigned short*)(lo + off) = l;
}

#define MFMA32(a, b, c) __builtin_amdgcn_mfma_f32_32x32x16_bf16((a), (b), (c), 0, 0, 0)
#define MFMA16(a, b, c) __builtin_amdgcn_mfma_f32_16x16x32_bf16((a), (b), (c), 0, 0, 0)

constexpr float BAND = 1e-3f;   // on v = prob*prev_m; ~70x est. bf16x3 error

// ---------------- pass A: split weights to bf16 hi/lo ----------------
__global__ __launch_bounds__(256) void split_weights(
    const float* __restrict__ W_L, const float* __restrict__ W_l1,
    const float* __restrict__ W_l2,
    unsigned short* __restrict__ WLh, unsigned short* __restrict__ WLl,
    unsigned short* __restrict__ W1h, unsigned short* __restrict__ W1l,
    unsigned short* __restrict__ W2h, unsigned short* __restrict__ W2l)
{
    const int g = blockIdx.x * 256 + threadIdx.x;   // grid sized exactly
    float x;
    unsigned short *ph, *pl;
    int idx;
    if (g < 262144)      { idx = g;          x = W_L[idx];  ph = WLh; pl = WLl; }
    else if (g < 393216) { idx = g - 262144; x = W_l1[idx]; ph = W1h; pl = W1l; }
    else                 { idx = g - 393216; x = W_l2[idx]; ph = W2h; pl = W2l; }
    const unsigned short h = f32_to_bf16(x);
    ph[idx] = h;
    pl[idx] = f32_to_bf16(x - bf16_to_f32(h));
}

// ---------------- pass B: fused MFMA MLP ----------------
// LDS map (bytes):
//  R0: [0..32K) A_hi | [32K..64K) A_lo   (pitch 1024)   -> later X2_hi [0..16K),
//      X2_lo [16K..32K) (pitch 512)
//  R1: [64K..96K) X1_hi | [96K..128K) X1_lo (pitch 1024) -> later X3 f32
//      (pitch 132 floats) at [64K..)
//  sM: 32 f32 at [128K..)
constexpr int SMEM_BYTES = 131072 + 128;

__global__ __launch_bounds__(NT, 2) void mlp_mfma(
    const float* __restrict__ input, const float* __restrict__ prev_m,
    const float* __restrict__ W_l3,
    const unsigned short* __restrict__ WLh, const unsigned short* __restrict__ WLl,
    const unsigned short* __restrict__ W1h, const unsigned short* __restrict__ W1l,
    const unsigned short* __restrict__ W2h, const unsigned short* __restrict__ W2l,
    float* __restrict__ out, float* __restrict__ mask_out, float* __restrict__ currm_out,
    unsigned int* __restrict__ ctr, int* __restrict__ list)
{
    __shared__ __attribute__((aligned(16))) char smem[SMEM_BYTES];
    char* Ahi = smem;
    char* Alo = smem + 32768;
    char* X1h = smem + 65536;
    char* X1l = smem + 98304;
    char* X2h = smem;
    char* X2l = smem + 16384;
    float* sX3 = (float*)(smem + 65536);      // [32][132] f32
    float* sM  = (float*)(smem + 131072);     // [32]

    const int tid  = threadIdx.x;
    const int lane = tid & 63;
    const int wid  = tid >> 6;
    const int row0 = blockIdx.x * TM;

    // ---- stage A: input rows -> bf16 hi/lo, swizzled ----
    #pragma unroll
    for (int i = 0; i < 8; ++i) {
        const int c  = i * NT + tid;           // 0..4095 float4-chunks
        const int r  = c >> 7;
        const int kq = (c & 127) << 2;         // element index (mult of 4)
        const float4 v = *(const float4*)&input[(size_t)(row0 + r) * D0 + kq];
        const unsigned short h0 = f32_to_bf16(v.x);
        const unsigned short h1 = f32_to_bf16(v.y);
        const unsigned short h2 = f32_to_bf16(v.z);
        const unsigned short h3 = f32_to_bf16(v.w);
        const unsigned short l0 = f32_to_bf16(v.x - bf16_to_f32(h0));
        const unsigned short l1 = f32_to_bf16(v.y - bf16_to_f32(h1));
        const unsigned short l2 = f32_to_bf16(v.z - bf16_to_f32(h2));
        const unsigned short l3 = f32_to_bf16(v.w - bf16_to_f32(h3));
        vus4 hv = {h0, h1, h2, h3};
        vus4 lv = {l0, l1, l2, l3};
        const int off = (r * 1024 + kq * 2) ^ ((r & 7) << 4);   // 8B-granular, swz-safe
        *(vus4*)(Ahi + off) = hv;
        *(vus4*)(Alo + off) = lv;
    }
    __syncthreads();   // B1

    // ---- GEMM1: X1 = gelu(A @ W_L^T), 32x512, K=512, 32x32x16 ----
    {
        const int e0 = wid * 64;               // wave owns n-tiles e0, e0+32
        vf16 acc0 = vzero16(), acc1 = vzero16();
        #pragma unroll 4
        for (int ks = 0; ks < 32; ++ks) {
            const int k0 = ks * 16;
            const int kk = k0 + ((lane >> 5) << 3);
            vshort8 ah  = ld_act32(Ahi, lane, 1024, k0);
            vshort8 al  = ld_act32(Alo, lane, 1024, k0);
            vshort8 b0h = ld_w(WLh, D0, e0 + (lane & 31), kk);
            vshort8 b0l = ld_w(WLl, D0, e0 + (lane & 31), kk);
            vshort8 b1h = ld_w(WLh, D0, e0 + 32 + (lane & 31), kk);
            vshort8 b1l = ld_w(WLl, D0, e0 + 32 + (lane & 31), kk);
            acc0 = MFMA32(ah, b0h, acc0);
            acc1 = MFMA32(ah, b1h, acc1);
            acc0 = MFMA32(al, b0h, acc0);
            acc1 = MFMA32(al, b1h, acc1);
            acc0 = MFMA32(ah, b0l, acc0);
            acc1 = MFMA32(ah, b1l, acc1);
        }
        // epilogue: gelu -> X1 hi/lo (R1; disjoint from A, no barrier needed)
        #pragma unroll
        for (int r = 0; r < 16; ++r) {
            const int row = (r & 3) + 8 * (r >> 2) + 4 * (lane >> 5);
            st_act(X1h, X1l, row, e0 + (lane & 31), 1024, gelu_exact(acc0[r]));
            st_act(X1h, X1l, row, e0 + 32 + (lane & 31), 1024, gelu_exact(acc1[r]));
        }
    }
    __syncthreads();   // B2

    // ---- GEMM2: X2 = gelu(X1 @ W_l1^T), 32x256, K=512, 32x32x16 ----
    {
        const int e0 = wid * 32;               // 8 n-tiles, one per wave
        vf16 accA = vzero16(), accB = vzero16();   // split chains for ILP
        #pragma unroll 2
        for (int ks = 0; ks < 32; ks += 2) {
            {
                const int k0 = ks * 16;
                const int kk = k0 + ((lane >> 5) << 3);
                vshort8 ah = ld_act32(X1h, lane, 1024, k0);
                vshort8 al = ld_act32(X1l, lane, 1024, k0);
                vshort8 bh = ld_w(W1h, D1, e0 + (lane & 31), kk);
                vshort8 bl = ld_w(W1l, D1, e0 + (lane & 31), kk);
                accA = MFMA32(ah, bh, accA);
                accA = MFMA32(al, bh, accA);
                accA = MFMA32(ah, bl, accA);
            }
            {
                const int k0 = ks * 16 + 16;
                const int kk = k0 + ((lane >> 5) << 3);
                vshort8 ah = ld_act32(X1h, lane, 1024, k0);
                vshort8 al = ld_act32(X1l, lane, 1024, k0);
                vshort8 bh = ld_w(W1h, D1, e0 + (lane & 31), kk);
                vshort8 bl = ld_w(W1l, D1, e0 + (lane & 31), kk);
                accB = MFMA32(ah, bh, accB);
                accB = MFMA32(al, bh, accB);
                accB = MFMA32(ah, bl, accB);
            }
        }
        vf16 acc = accA + accB;
        // epilogue -> X2 hi/lo in R0 (A is dead; pitch 512)
        #pragma unroll
        for (int r = 0; r < 16; ++r) {
            const int row = (r & 3) + 8 * (r >> 2) + 4 * (lane >> 5);
            st_act(X2h, X2l, row, e0 + (lane & 31), 512, gelu_exact(acc[r]));
        }
    }
    __syncthreads();   // B3

    // ---- GEMM3: X3 = gelu(X2 @ W_l2^T), 32x128, K=256, 16x16x32 ----
    {
        const int e0 = wid * 16;               // 8 n-tiles, one per wave
        vf4 acc0 = vzero4(), acc1 = vzero4();  // m-tiles rows 0..15, 16..31
        #pragma unroll 2
        for (int ks = 0; ks < 8; ++ks) {
            const int k0 = ks * 32;
            const int kk = k0 + ((lane >> 4) << 3);
            vshort8 bh  = ld_w(W2h, D2, e0 + (lane & 15), kk);
            vshort8 bl  = ld_w(W2l, D2, e0 + (lane & 15), kk);
            vshort8 ah0 = ld_act16(X2h, lane, 512, 0, k0);
            vshort8 al0 = ld_act16(X2l, lane, 512, 0, k0);
            vshort8 ah1 = ld_act16(X2h, lane, 512, 16, k0);
            vshort8 al1 = ld_act16(X2l, lane, 512, 16, k0);
            acc0 = MFMA16(ah0, bh, acc0);
            acc1 = MFMA16(ah1, bh, acc1);
            acc0 = MFMA16(al0, bh, acc0);
            acc1 = MFMA16(al1, bh, acc1);
            acc0 = MFMA16(ah0, bl, acc0);
            acc1 = MFMA16(ah1, bl, acc1);
        }
        // epilogue -> X3 f32 in R1 (X1 dead); pitch 132 floats
        #pragma unroll
        for (int r = 0; r < 4; ++r) {
            const int rr = ((lane >> 4) << 2) + r;
            sX3[rr * 132 + e0 + (lane & 15)]        = gelu_exact(acc0[r]);
            sX3[(rr + 16) * 132 + e0 + (lane & 15)] = gelu_exact(acc1[r]);
        }
    }
    __syncthreads();   // B4

    // ---- layer4 (fp32) + decision + flag ----
    {
        const int row = tid >> 4;              // 32 rows x 16 lanes
        const int j   = tid & 15;
        float p = 0.0f;
        #pragma unroll
        for (int t = 0; t < 8; ++t)
            p = fmaf(sX3[row * 132 + j + 16 * t], W_l3[j + 16 * t], p);
        #pragma unroll
        for (int off = 8; off > 0; off >>= 1)
            p += __shfl_down(p, off, 16);
        if (j == 0) {
            const float prob = 1.0f / (1.0f + expf(-p));
            const float v    = prob * prev_m[row0 + row];
            const float st   = (v > 0.5f) ? 1.0f : 0.0f;
            const float cm   = st + 1e-10f;
            sM[row] = cm;
            mask_out[row0 + row]  = st;
            currm_out[row0 + row] = cm;
            if (fabsf(v - 0.5f) < BAND) {
                const unsigned int slot = atomicAdd(ctr, 1u);
                list[slot] = row0 + row;
            }
        }
    }
    __syncthreads();   // B5

    // ---- epilogue: out = input * curr_m ----
    #pragma unroll
    for (int it = 0; it < 8; ++it) {
        const int j = tid + NT * it;           // 4096 float4 = 32 rows x 128
        const int r = j >> 7;
        const int q = (j & 127) << 2;
        const float m = sM[r];
        const float4 v = *(const float4*)&input[(size_t)(row0 + r) * D0 + q];
        float4 o;
        o.x = v.x * m; o.y = v.y * m; o.z = v.z * m; o.w = v.w * m;
        *(float4*)&out[(size_t)(row0 + r) * D0 + q] = o;
    }
}

// ---------------- pass C: exact fp32 recompute of flagged rows ----------------
// 8 rows per block-iteration so weight reads amortize (L2 traffic /8).
__global__ __launch_bounds__(256) void fix_rows(
    const float* __restrict__ input, const float* __restrict__ prev_m,
    const float* __restrict__ W_L, const float* __restrict__ W_l1,
    const float* __restrict__ W_l2, const float* __restrict__ W_l3,
    const unsigned int* __restrict__ ctr, const int* __restrict__ list,
    float* __restrict__ out, float* __restrict__ mask_out, float* __restrict__ currm_out)
{
    __shared__ float sx[8][512];
    __shared__ float s1[8][512];
    __shared__ float s2[8][256];
    __shared__ float s3[8][128];
    __shared__ float scm[8];
    const int tid = threadIdx.x;
    const int n = (int)*ctr;

    for (int base = blockIdx.x * 8; base < n; base += gridDim.x * 8) {
        int cnt = n - base;
        if (cnt > 8) cnt = 8;
        __syncthreads();                       // protect prev iteration LDS
        #pragma unroll
        for (int g = 0; g < 8; ++g) {
            if (g < cnt) {
                const int row = list[base + g];
                for (int j = tid; j < 512; j += 256)
                    sx[g][j] = input[(size_t)row * 512 + j];
            } else {
                for (int j = tid; j < 512; j += 256) sx[g][j] = 0.0f;
            }
        }
        __syncthreads();
        // L1: e = tid, tid+256
        #pragma unroll
        for (int half = 0; half < 2; ++half) {
            const int e = tid + half * 256;
            const float4* wr = (const float4*)&W_L[e * 512];
            float a[8];
            #pragma unroll
            for (int g = 0; g < 8; ++g) a[g] = 0.0f;
            for (int kq = 0; kq < 128; ++kq) {
                const float4 w = wr[kq];
                #pragma unroll
                for (int g = 0; g < 8; ++g) {
                    const float4 xv = *(const float4*)&sx[g][kq * 4];
                    a[g] = fmaf(xv.x, w.x, a[g]); a[g] = fmaf(xv.y, w.y, a[g]);
                    a[g] = fmaf(xv.z, w.z, a[g]); a[g] = fmaf(xv.w, w.w, a[g]);
                }
            }
            #pragma unroll
            for (int g = 0; g < 8; ++g) s1[g][e] = gelu_exact(a[g]);
        }
        __syncthreads();
        // L2: e = tid
        {
            const int e = tid;
            const float4* wr = (const float4*)&W_l1[e * 512];
            float a[8];
            #pragma unroll
            for (int g = 0; g < 8; ++g) a[g] = 0.0f;
            for (int kq = 0; kq < 128; ++kq) {
                const float4 w = wr[kq];
                #pragma unroll
                for (int g = 0; g < 8; ++g) {
                    const float4 xv = *(const float4*)&s1[g][kq * 4];
                    a[g] = fmaf(xv.x, w.x, a[g]); a[g] = fmaf(xv.y, w.y, a[g]);
                    a[g] = fmaf(xv.z, w.z, a[g]); a[g] = fmaf(xv.w, w.w, a[g]);
                }
            }
            #pragma unroll
            for (int g = 0; g < 8; ++g) s2[g][e] = gelu_exact(a[g]);
        }
        __syncthreads();
        // L3: e = tid < 128
        if (tid < 128) {
            const int e = tid;
            const float4* wr = (const float4*)&W_l2[e * 256];
            float a[8];
            #pragma unroll
            for (int g = 0; g < 8; ++g) a[g] = 0.0f;
            for (int kq = 0; kq < 64; ++kq) {
                const float4 w = wr[kq];
                #pragma unroll
                for (int g = 0; g < 8; ++g) {
                    const float4 xv = *(const float4*)&s2[g][kq * 4];
                    a[g] = fmaf(xv.x, w.x, a[g]); a[g] = fmaf(xv.y, w.y, a[g]);
                    a[g] = fmaf(xv.z, w.z, a[g]); a[g] = fmaf(xv.w, w.w, a[g]);
                }
            }
            #pragma unroll
            for (int g = 0; g < 8; ++g) s3[g][e] = gelu_exact(a[g]);
        }
        __syncthreads();
        // L4 + decision: 8 rows x 16 lanes
        if (tid < 128) {
            const int g = tid >> 4, j = tid & 15;
            float p = 0.0f;
            #pragma unroll
            for (int t = 0; t < 8; ++t)
                p = fmaf(s3[g][j + 16 * t], W_l3[j + 16 * t], p);
            #pragma unroll
            for (int off = 8; off > 0; off >>= 1)
                p += __shfl_down(p, off, 16);
            if (j == 0 && g < cnt) {
                const int row = list[base + g];
                const float prob = 1.0f / (1.0f + expf(-p));
                const float v    = prob * prev_m[row];
                const float st   = (v > 0.5f) ? 1.0f : 0.0f;
                const float cm   = st + 1e-10f;
                mask_out[row]  = st;
                currm_out[row] = cm;
                scm[g] = cm;
            }
        }
        __syncthreads();
        // rewrite out rows
        for (int idx = tid; idx < cnt * 128; idx += 256) {
            const int g = idx >> 7;
            const int q = (idx & 127) << 2;
            const int row = list[base + g];
            const float cm = scm[g];
            const float4 v = *(const float4*)&input[(size_t)row * 512 + q];
            float4 o;
            o.x = v.x * cm; o.y = v.y * cm; o.z = v.z * cm; o.w = v.w * cm;
            *(float4*)&out[(size_t)row * 512 + q] = o;
        }
    }
}

}  // namespace

extern "C" void kernel_launch(void* const* d_in, const int* in_sizes, int n_in,
                              void* d_out, int out_size, void* d_ws, size_t ws_size,
                              hipStream_t stream) {
    const float* input  = (const float*)d_in[0];
    // d_in[1] = attention_mask: unused by the reference computation
    const float* prev_m = (const float*)d_in[2];
    const float* W_L    = (const float*)d_in[3];
    const float* W_l1   = (const float*)d_in[4];
    const float* W_l2   = (const float*)d_in[5];
    const float* W_l3   = (const float*)d_in[6];

    float* out_p   = (float*)d_out;                  // [R, 512]
    float* mask_p  = out_p + (size_t)R_ROWS * D0;    // [R]
    float* currm_p = mask_p + R_ROWS;                // [R]

    // workspace layout (bytes): ctr @0, list @1024 (256KB), then split weights
    char* ws = (char*)d_ws;
    unsigned int* ctr = (unsigned int*)ws;
    int* list = (int*)(ws + 1024);
    unsigned short* WLh = (unsigned short*)(ws + 263168);
    unsigned short* WLl = (unsigned short*)(ws + 787456);
    unsigned short* W1h = (unsigned short*)(ws + 1311744);
    unsigned short* W1l = (unsigned short*)(ws + 1573888);
    unsigned short* W2h = (unsigned short*)(ws + 1836032);
    unsigned short* W2l = (unsigned short*)(ws + 1901568);
    // total ws use: 1967104 bytes

    hipMemsetAsync(ctr, 0, sizeof(unsigned int), stream);
    split_weights<<<1664, 256, 0, stream>>>(W_L, W_l1, W_l2,
                                            WLh, WLl, W1h, W1l, W2h, W2l);
    mlp_mfma<<<R_ROWS / TM, NT, 0, stream>>>(input, prev_m, W_l3,
                                             WLh, WLl, W1h, W1l, W2h, W2l,
                                             out_p, mask_p, currm_p, ctr, list);
    fix_rows<<<1024, 256, 0, stream>>>(input, prev_m, W_L, W_l1, W_l2, W_l3,
                                       ctr, list, out_p, mask_p, currm_p);
}

// Round 2
// 299.871 us; speedup vs baseline: 3.0462x; 1.9201x over previous
//
#include <hip/hip_runtime.h>
#include <math.h>

// infoFSM mask-scorer MLP — Round 4: bf16x3 MFMA + packed fragment weights +
// LDS overlay for 2 blocks/CU.
//
// R3 (576us) was latency-bound: MfmaUtil 12.6, VALUBusy 18, occupancy 23%
// (LDS 131KB -> 1 block/CU) and per-lane weight reads scattered over 32-64
// cache lines per wave load. R4:
//  - pass A packs weight hi/lo bf16 into MFMA *fragment order*:
//    [tile][hi/lo][lane][8]  -> wave load = base + lane*16, fully coalesced.
//  - pass B LDS overlay: A and X1 share one 64KB region (barrier between
//    GEMM1 k-loop and its epilogue); X2/X3/sM overlay the same region.
//    LDS 65536 B -> 2 blocks/CU, 4 waves/SIMD. K-loops have no barriers.
//  - numerics identical to R3 (bf16x3, band 1e-3, exact fp32 fix pass).

namespace {

constexpr int R_ROWS = 128 * 512;   // 65536
constexpr int D0 = 512, D1 = 512, D2 = 256, D3 = 128;
constexpr int TM = 32;              // rows per block (pass B)
constexpr int NT = 512;             // 8 waves

typedef __attribute__((ext_vector_type(8)))  short          vshort8;
typedef __attribute__((ext_vector_type(4)))  unsigned short vus4;
typedef __attribute__((ext_vector_type(8)))  unsigned short vus8;
typedef __attribute__((ext_vector_type(16))) float          vf16;
typedef __attribute__((ext_vector_type(4)))  float          vf4;

// ---------------- helpers ----------------
__device__ __forceinline__ unsigned short f32_to_bf16(float x) {
    unsigned int b = __float_as_uint(x);
    b += 0x7FFFu + ((b >> 16) & 1u);          // RNE (inputs finite)
    return (unsigned short)(b >> 16);
}
__device__ __forceinline__ float bf16_to_f32(unsigned short h) {
    return __uint_as_float(((unsigned int)h) << 16);
}
__device__ __forceinline__ float gelu_exact(float x) {
    return 0.5f * x * (1.0f + erff(x * 0.70710678118654752440f));
}
__device__ __forceinline__ vf16 vzero16() {
    vf16 v;
    #pragma unroll
    for (int i = 0; i < 16; ++i) v[i] = 0.0f;
    return v;
}
__device__ __forceinline__ vf4 vzero4() {
    vf4 v;
    #pragma unroll
    for (int i = 0; i < 4; ++i) v[i] = 0.0f;
    return v;
}

// LDS activation tiles: [row][k] bf16, XOR-swizzle bits 4..6.
__device__ __forceinline__ int swz_off(int row, int colElem, int pitchB) {
    return (row * pitchB + colElem * 2) ^ ((row & 7) << 4);
}
__device__ __forceinline__ vshort8 ld_act32(const char* base, int lane, int pitchB, int k0) {
    const int row = lane & 31;
    const int k = k0 + ((lane >> 5) << 3);
    return *(const vshort8*)(base + swz_off(row, k, pitchB));
}
__device__ __forceinline__ vshort8 ld_act16(const char* base, int lane, int pitchB, int row0, int k0) {
    const int row = row0 + (lane & 15);
    const int k = k0 + ((lane >> 4) << 3);
    return *(const vshort8*)(base + swz_off(row, k, pitchB));
}
// packed weight fragment: P + blk*2048B + part*1024B + lane*16B
__device__ __forceinline__ vshort8 ld_pack(const unsigned short* __restrict__ P,
                                           int blk, int part, int lane) {
    return *(const vshort8*)((const char*)P + (((size_t)blk) << 11) +
                             (part << 10) + (lane << 4));
}
__device__ __forceinline__ void st_act(char* hi, char* lo, int row, int col, int pitchB, float x) {
    const unsigned short h = f32_to_bf16(x);
    const unsigned short l = f32_to_bf16(x - bf16_to_f32(h));
    const int off = swz_off(row, col, pitchB);
    *(unsigned short*)(hi + off) = h;
    *(unsigned short*)(lo + off) = l;
}

#define MFMA32(a, b, c) __builtin_amdgcn_mfma_f32_32x32x16_bf16((a), (b), (c), 0, 0, 0)
#define MFMA16(a, b, c) __builtin_amdgcn_mfma_f32_16x16x32_bf16((a), (b), (c), 0, 0, 0)

constexpr float BAND = 1e-3f;   // on v = prob*prev_m; ~70x est. bf16x3 error

// ---------------- pass A: split + pack weights into fragment order ----------
// P1: GEMM1 (32x32x16, N=512,K=512): blk = nt*32+ks, nt=0..15, ks=0..31
//     lane l -> W_L[nt*32 + (l&31)][ks*16 + (l>>5)*8 + j]
// P2: GEMM2 (32x32x16, N=256,K=512): blk = nt*32+ks, nt=0..7
//     lane l -> W_l1[nt*32 + (l&31)][ks*16 + (l>>5)*8 + j]
// P3: GEMM3 (16x16x32, N=128,K=256): blk = nt*8+ks, nt=0..7, ks=0..7
//     lane l -> W_l2[nt*16 + (l&15)][ks*32 + (l>>4)*8 + j]
__global__ __launch_bounds__(256) void pack_weights(
    const float* __restrict__ W_L, const float* __restrict__ W_l1,
    const float* __restrict__ W_l2,
    unsigned short* __restrict__ P1, unsigned short* __restrict__ P2,
    unsigned short* __restrict__ P3)
{
    const int g = blockIdx.x * 256 + threadIdx.x;   // 53248 threads total
    const float* src;
    unsigned short* dst;
    int e, k, K, blk, lane;
    if (g < 32768) {
        lane = g & 63;
        const int ks = (g >> 6) & 31, nt = g >> 11;
        src = W_L; K = 512; dst = P1;
        e = nt * 32 + (lane & 31);
        k = ks * 16 + ((lane >> 5) << 3);
        blk = nt * 32 + ks;
    } else if (g < 49152) {
        const int h = g - 32768;
        lane = h & 63;
        const int ks = (h >> 6) & 31, nt = h >> 11;
        src = W_l1; K = 512; dst = P2;
        e = nt * 32 + (lane & 31);
        k = ks * 16 + ((lane >> 5) << 3);
        blk = nt * 32 + ks;
    } else {
        const int h = g - 49152;
        lane = h & 63;
        const int ks = (h >> 6) & 7, nt = h >> 9;
        src = W_l2; K = 256; dst = P3;
        e = nt * 16 + (lane & 15);
        k = ks * 32 + ((lane >> 4) << 3);
        blk = nt * 8 + ks;
    }
    const float4 v0 = *(const float4*)&src[(size_t)e * K + k];
    const float4 v1 = *(const float4*)&src[(size_t)e * K + k + 4];
    const float xs[8] = {v0.x, v0.y, v0.z, v0.w, v1.x, v1.y, v1.z, v1.w};
    vus8 hv, lv;
    #pragma unroll
    for (int j = 0; j < 8; ++j) {
        const unsigned short h = f32_to_bf16(xs[j]);
        hv[j] = h;
        lv[j] = f32_to_bf16(xs[j] - bf16_to_f32(h));
    }
    unsigned short* base = dst + ((size_t)blk << 10);   // 1024 shorts per blk
    *(vus8*)(base + lane * 8)       = hv;
    *(vus8*)(base + 512 + lane * 8) = lv;
}

// ---------------- pass B: fused MFMA MLP ----------------
// LDS overlay (bytes), one 64KB region:
//   stage A:  Ahi [0,32K)   Alo [32K,64K)        pitch 1024
//   GEMM1 ep: X1h [0,32K)   X1l [32K,64K)        pitch 1024  (A dead, barrier)
//   GEMM2 ep: X2h [0,16K)   X2l [16K,32K)        pitch 512   (X1 dead, barrier)
//   GEMM3 ep: X3  [32K, 32K+16896) f32 pitch 132 (disjoint from X2)
//   sM at [49664, 49792)
constexpr int SMEM_BYTES = 65536;

__global__ __launch_bounds__(NT, 4) void mlp_mfma(
    const float* __restrict__ input, const float* __restrict__ prev_m,
    const float* __restrict__ W_l3,
    const unsigned short* __restrict__ P1, const unsigned short* __restrict__ P2,
    const unsigned short* __restrict__ P3,
    float* __restrict__ out, float* __restrict__ mask_out, float* __restrict__ currm_out,
    unsigned int* __restrict__ ctr, int* __restrict__ list)
{
    __shared__ __attribute__((aligned(16))) char smem[SMEM_BYTES];
    char* Ahi = smem;
    char* Alo = smem + 32768;
    char* X1h = smem;
    char* X1l = smem + 32768;
    char* X2h = smem;
    char* X2l = smem + 16384;
    float* sX3 = (float*)(smem + 32768);      // [32][132] f32
    float* sM  = (float*)(smem + 49664);      // [32]

    const int tid  = threadIdx.x;
    const int lane = tid & 63;
    const int wid  = tid >> 6;
    const int row0 = blockIdx.x * TM;

    // ---- stage A: input rows -> bf16 hi/lo, swizzled ----
    #pragma unroll
    for (int i = 0; i < 8; ++i) {
        const int c  = i * NT + tid;           // 0..4095 float4-chunks
        const int r  = c >> 7;
        const int kq = (c & 127) << 2;
        const float4 v = *(const float4*)&input[(size_t)(row0 + r) * D0 + kq];
        const unsigned short h0 = f32_to_bf16(v.x);
        const unsigned short h1 = f32_to_bf16(v.y);
        const unsigned short h2 = f32_to_bf16(v.z);
        const unsigned short h3 = f32_to_bf16(v.w);
        const unsigned short l0 = f32_to_bf16(v.x - bf16_to_f32(h0));
        const unsigned short l1 = f32_to_bf16(v.y - bf16_to_f32(h1));
        const unsigned short l2 = f32_to_bf16(v.z - bf16_to_f32(h2));
        const unsigned short l3 = f32_to_bf16(v.w - bf16_to_f32(h3));
        vus4 hv = {h0, h1, h2, h3};
        vus4 lv = {l0, l1, l2, l3};
        const int off = (r * 1024 + kq * 2) ^ ((r & 7) << 4);
        *(vus4*)(Ahi + off) = hv;
        *(vus4*)(Alo + off) = lv;
    }
    __syncthreads();   // B1: A staged

    // ---- GEMM1: X1 = gelu(A @ W_L^T), 32x512, K=512, 32x32x16 ----
    vf16 g1acc0, g1acc1;
    {
        const int nt0 = wid * 2;               // wave owns n-tiles nt0, nt0+1
        vf16 acc0 = vzero16(), acc1 = vzero16();
        #pragma unroll 4
        for (int ks = 0; ks < 32; ++ks) {
            const int k0 = ks * 16;
            vshort8 ah  = ld_act32(Ahi, lane, 1024, k0);
            vshort8 al  = ld_act32(Alo, lane, 1024, k0);
            vshort8 b0h = ld_pack(P1, nt0 * 32 + ks, 0, lane);
            vshort8 b0l = ld_pack(P1, nt0 * 32 + ks, 1, lane);
            vshort8 b1h = ld_pack(P1, (nt0 + 1) * 32 + ks, 0, lane);
            vshort8 b1l = ld_pack(P1, (nt0 + 1) * 32 + ks, 1, lane);
            acc0 = MFMA32(ah, b0h, acc0);
            acc1 = MFMA32(ah, b1h, acc1);
            acc0 = MFMA32(al, b0h, acc0);
            acc1 = MFMA32(al, b1h, acc1);
            acc0 = MFMA32(ah, b0l, acc0);
            acc1 = MFMA32(ah, b1l, acc1);
        }
        g1acc0 = acc0; g1acc1 = acc1;
    }
    __syncthreads();   // B2a: all waves done reading A
    {
        const int e0 = wid * 64;
        #pragma unroll
        for (int r = 0; r < 16; ++r) {
            const int row = (r & 3) + 8 * (r >> 2) + 4 * (lane >> 5);
            st_act(X1h, X1l, row, e0 + (lane & 31), 1024, gelu_exact(g1acc0[r]));
            st_act(X1h, X1l, row, e0 + 32 + (lane & 31), 1024, gelu_exact(g1acc1[r]));
        }
    }
    __syncthreads();   // B2b: X1 ready

    // ---- GEMM2: X2 = gelu(X1 @ W_l1^T), 32x256, K=512, 32x32x16 ----
    vf16 g2acc;
    {
        vf16 accA = vzero16(), accB = vzero16();
        #pragma unroll 2
        for (int ks = 0; ks < 32; ks += 2) {
            {
                const int k0 = ks * 16;
                vshort8 ah = ld_act32(X1h, lane, 1024, k0);
                vshort8 al = ld_act32(X1l, lane, 1024, k0);
                vshort8 bh = ld_pack(P2, wid * 32 + ks, 0, lane);
                vshort8 bl = ld_pack(P2, wid * 32 + ks, 1, lane);
                accA = MFMA32(ah, bh, accA);
                accA = MFMA32(al, bh, accA);
                accA = MFMA32(ah, bl, accA);
            }
            {
                const int k0 = ks * 16 + 16;
                vshort8 ah = ld_act32(X1h, lane, 1024, k0);
                vshort8 al = ld_act32(X1l, lane, 1024, k0);
                vshort8 bh = ld_pack(P2, wid * 32 + ks + 1, 0, lane);
                vshort8 bl = ld_pack(P2, wid * 32 + ks + 1, 1, lane);
                accB = MFMA32(ah, bh, accB);
                accB = MFMA32(al, bh, accB);
                accB = MFMA32(ah, bl, accB);
            }
        }
        g2acc = accA + accB;
    }
    __syncthreads();   // B3a: all waves done reading X1
    {
        const int e0 = wid * 32;
        #pragma unroll
        for (int r = 0; r < 16; ++r) {
            const int row = (r & 3) + 8 * (r >> 2) + 4 * (lane >> 5);
            st_act(X2h, X2l, row, e0 + (lane & 31), 512, gelu_exact(g2acc[r]));
        }
    }
    __syncthreads();   // B3b: X2 ready

    // ---- GEMM3: X3 = gelu(X2 @ W_l2^T), 32x128, K=256, 16x16x32 ----
    {
        const int e0 = wid * 16;
        vf4 acc0 = vzero4(), acc1 = vzero4();  // rows 0..15, 16..31
        #pragma unroll 2
        for (int ks = 0; ks < 8; ++ks) {
            const int k0 = ks * 32;
            vshort8 bh  = ld_pack(P3, wid * 8 + ks, 0, lane);
            vshort8 bl  = ld_pack(P3, wid * 8 + ks, 1, lane);
            vshort8 ah0 = ld_act16(X2h, lane, 512, 0, k0);
            vshort8 al0 = ld_act16(X2l, lane, 512, 0, k0);
            vshort8 ah1 = ld_act16(X2h, lane, 512, 16, k0);
            vshort8 al1 = ld_act16(X2l, lane, 512, 16, k0);
            acc0 = MFMA16(ah0, bh, acc0);
            acc1 = MFMA16(ah1, bh, acc1);
            acc0 = MFMA16(al0, bh, acc0);
            acc1 = MFMA16(al1, bh, acc1);
            acc0 = MFMA16(ah0, bl, acc0);
            acc1 = MFMA16(ah1, bl, acc1);
        }
        // X3 region [32K,49.6K) disjoint from X2 [0,32K): no pre-barrier needed
        #pragma unroll
        for (int r = 0; r < 4; ++r) {
            const int rr = ((lane >> 4) << 2) + r;
            sX3[rr * 132 + e0 + (lane & 15)]        = gelu_exact(acc0[r]);
            sX3[(rr + 16) * 132 + e0 + (lane & 15)] = gelu_exact(acc1[r]);
        }
    }
    __syncthreads();   // B4: X3 ready

    // ---- layer4 (fp32) + decision + flag ----
    {
        const int row = tid >> 4;              // 32 rows x 16 lanes
        const int j   = tid & 15;
        float p = 0.0f;
        #pragma unroll
        for (int t = 0; t < 8; ++t)
            p = fmaf(sX3[row * 132 + j + 16 * t], W_l3[j + 16 * t], p);
        #pragma unroll
        for (int off = 8; off > 0; off >>= 1)
            p += __shfl_down(p, off, 16);
        if (j == 0) {
            const float prob = 1.0f / (1.0f + expf(-p));
            const float v    = prob * prev_m[row0 + row];
            const float st   = (v > 0.5f) ? 1.0f : 0.0f;
            const float cm   = st + 1e-10f;
            sM[row] = cm;
            mask_out[row0 + row]  = st;
            currm_out[row0 + row] = cm;
            if (fabsf(v - 0.5f) < BAND) {
                const unsigned int slot = atomicAdd(ctr, 1u);
                list[slot] = row0 + row;
            }
        }
    }
    __syncthreads();   // B5: sM ready

    // ---- epilogue: out = input * curr_m ----
    #pragma unroll
    for (int it = 0; it < 8; ++it) {
        const int j = tid + NT * it;           // 4096 float4 = 32 rows x 128
        const int r = j >> 7;
        const int q = (j & 127) << 2;
        const float m = sM[r];
        const float4 v = *(const float4*)&input[(size_t)(row0 + r) * D0 + q];
        float4 o;
        o.x = v.x * m; o.y = v.y * m; o.z = v.z * m; o.w = v.w * m;
        *(float4*)&out[(size_t)(row0 + r) * D0 + q] = o;
    }
}

// ---------------- pass C: exact fp32 recompute of flagged rows ----------------
__global__ __launch_bounds__(256) void fix_rows(
    const float* __restrict__ input, const float* __restrict__ prev_m,
    const float* __restrict__ W_L, const float* __restrict__ W_l1,
    const float* __restrict__ W_l2, const float* __restrict__ W_l3,
    const unsigned int* __restrict__ ctr, const int* __restrict__ list,
    float* __restrict__ out, float* __restrict__ mask_out, float* __restrict__ currm_out)
{
    __shared__ float sx[8][512];
    __shared__ float s1[8][512];
    __shared__ float s2[8][256];
    __shared__ float s3[8][128];
    __shared__ float scm[8];
    const int tid = threadIdx.x;
    const int n = (int)*ctr;

    for (int base = blockIdx.x * 8; base < n; base += gridDim.x * 8) {
        int cnt = n - base;
        if (cnt > 8) cnt = 8;
        __syncthreads();                       // protect prev iteration LDS
        #pragma unroll
        for (int g = 0; g < 8; ++g) {
            if (g < cnt) {
                const int row = list[base + g];
                for (int j = tid; j < 512; j += 256)
                    sx[g][j] = input[(size_t)row * 512 + j];
            } else {
                for (int j = tid; j < 512; j += 256) sx[g][j] = 0.0f;
            }
        }
        __syncthreads();
        #pragma unroll
        for (int half = 0; half < 2; ++half) {
            const int e = tid + half * 256;
            const float4* wr = (const float4*)&W_L[e * 512];
            float a[8];
            #pragma unroll
            for (int g = 0; g < 8; ++g) a[g] = 0.0f;
            for (int kq = 0; kq < 128; ++kq) {
                const float4 w = wr[kq];
                #pragma unroll
                for (int g = 0; g < 8; ++g) {
                    const float4 xv = *(const float4*)&sx[g][kq * 4];
                    a[g] = fmaf(xv.x, w.x, a[g]); a[g] = fmaf(xv.y, w.y, a[g]);
                    a[g] = fmaf(xv.z, w.z, a[g]); a[g] = fmaf(xv.w, w.w, a[g]);
                }
            }
            #pragma unroll
            for (int g = 0; g < 8; ++g) s1[g][e] = gelu_exact(a[g]);
        }
        __syncthreads();
        {
            const int e = tid;
            const float4* wr = (const float4*)&W_l1[e * 512];
            float a[8];
            #pragma unroll
            for (int g = 0; g < 8; ++g) a[g] = 0.0f;
            for (int kq = 0; kq < 128; ++kq) {
                const float4 w = wr[kq];
                #pragma unroll
                for (int g = 0; g < 8; ++g) {
                    const float4 xv = *(const float4*)&s1[g][kq * 4];
                    a[g] = fmaf(xv.x, w.x, a[g]); a[g] = fmaf(xv.y, w.y, a[g]);
                    a[g] = fmaf(xv.z, w.z, a[g]); a[g] = fmaf(xv.w, w.w, a[g]);
                }
            }
            #pragma unroll
            for (int g = 0; g < 8; ++g) s2[g][e] = gelu_exact(a[g]);
        }
        __syncthreads();
        if (tid < 128) {
            const int e = tid;
            const float4* wr = (const float4*)&W_l2[e * 256];
            float a[8];
            #pragma unroll
            for (int g = 0; g < 8; ++g) a[g] = 0.0f;
            for (int kq = 0; kq < 64; ++kq) {
                const float4 w = wr[kq];
                #pragma unroll
                for (int g = 0; g < 8; ++g) {
                    const float4 xv = *(const float4*)&s2[g][kq * 4];
                    a[g] = fmaf(xv.x, w.x, a[g]); a[g] = fmaf(xv.y, w.y, a[g]);
                    a[g] = fmaf(xv.z, w.z, a[g]); a[g] = fmaf(xv.w, w.w, a[g]);
                }
            }
            #pragma unroll
            for (int g = 0; g < 8; ++g) s3[g][e] = gelu_exact(a[g]);
        }
        __syncthreads();
        if (tid < 128) {
            const int g = tid >> 4, j = tid & 15;
            float p = 0.0f;
            #pragma unroll
            for (int t = 0; t < 8; ++t)
                p = fmaf(s3[g][j + 16 * t], W_l3[j + 16 * t], p);
            #pragma unroll
            for (int off = 8; off > 0; off >>= 1)
                p += __shfl_down(p, off, 16);
            if (j == 0 && g < cnt) {
                const int row = list[base + g];
                const float prob = 1.0f / (1.0f + expf(-p));
                const float v    = prob * prev_m[row];
                const float st   = (v > 0.5f) ? 1.0f : 0.0f;
                const float cm   = st + 1e-10f;
                mask_out[row]  = st;
                currm_out[row] = cm;
                scm[g] = cm;
            }
        }
        __syncthreads();
        for (int idx = tid; idx < cnt * 128; idx += 256) {
            const int g = idx >> 7;
            const int q = (idx & 127) << 2;
            const int row = list[base + g];
            const float cm = scm[g];
            const float4 v = *(const float4*)&input[(size_t)row * 512 + q];
            float4 o;
            o.x = v.x * cm; o.y = v.y * cm; o.z = v.z * cm; o.w = v.w * cm;
            *(float4*)&out[(size_t)row * 512 + q] = o;
        }
    }
}

}  // namespace

extern "C" void kernel_launch(void* const* d_in, const int* in_sizes, int n_in,
                              void* d_out, int out_size, void* d_ws, size_t ws_size,
                              hipStream_t stream) {
    const float* input  = (const float*)d_in[0];
    // d_in[1] = attention_mask: unused by the reference computation
    const float* prev_m = (const float*)d_in[2];
    const float* W_L    = (const float*)d_in[3];
    const float* W_l1   = (const float*)d_in[4];
    const float* W_l2   = (const float*)d_in[5];
    const float* W_l3   = (const float*)d_in[6];

    float* out_p   = (float*)d_out;                  // [R, 512]
    float* mask_p  = out_p + (size_t)R_ROWS * D0;    // [R]
    float* currm_p = mask_p + R_ROWS;                // [R]

    // workspace (bytes): ctr @0, list @1024 (256KB), packed weights after
    char* ws = (char*)d_ws;
    unsigned int* ctr = (unsigned int*)ws;
    int* list = (int*)(ws + 1024);
    unsigned short* P1 = (unsigned short*)(ws + 263168);    // 1 MB
    unsigned short* P2 = (unsigned short*)(ws + 1311744);   // 512 KB
    unsigned short* P3 = (unsigned short*)(ws + 1836032);   // 128 KB
    // total ws use: 1967104 bytes

    hipMemsetAsync(ctr, 0, sizeof(unsigned int), stream);
    pack_weights<<<208, 256, 0, stream>>>(W_L, W_l1, W_l2, P1, P2, P3);
    mlp_mfma<<<R_ROWS / TM, NT, 0, stream>>>(input, prev_m, W_l3,
                                             P1, P2, P3,
                                             out_p, mask_p, currm_p, ctr, list);
    fix_rows<<<1024, 256, 0, stream>>>(input, prev_m, W_L, W_l1, W_l2, W_l3,
                                       ctr, list, out_p, mask_p, currm_p);
}